// Round 2
// baseline (1799.484 us; speedup 1.0000x reference)
//
#include <hip/hip_runtime.h>
#include <hip/hip_fp16.h>

typedef _Float16 f16;
typedef _Float16 f16x8 __attribute__((ext_vector_type(8)));
typedef float    f32x4 __attribute__((ext_vector_type(4)));

#define SCALE_Q 0.08838834764831845f  // 1/sqrt(128), folded into Wq_eff & bq_eff

// pair p: 0..5 = Q of module p (A = xn of q-source), 6..11 = K of module p-6 (A = xn of kv-source)
// xn slots: 0=text 1=image 2=audio 3=agent
__constant__ int c_slot[12] = {0,0,0,1,1,2, 1,2,3,2,3,3};

__device__ __forceinline__ f32x4 vmax4(f32x4 a, f32x4 b){
  f32x4 r; r[0]=fmaxf(a[0],b[0]); r[1]=fmaxf(a[1],b[1]); r[2]=fmaxf(a[2],b[2]); r[3]=fmaxf(a[3],b[3]); return r;
}
__device__ __forceinline__ f32x4 vexp4(f32x4 a){
  f32x4 r; r[0]=__expf(a[0]); r[1]=__expf(a[1]); r[2]=__expf(a[2]); r[3]=__expf(a[3]); return r;
}
__device__ __forceinline__ f32x4 shflx4(f32x4 a, int m){
  f32x4 r; r[0]=__shfl_xor(a[0],m); r[1]=__shfl_xor(a[1],m); r[2]=__shfl_xor(a[2],m); r[3]=__shfl_xor(a[3],m); return r;
}

// async global->LDS, 16B per lane; LDS dest = wave-uniform base + lane*16 (m104/m108)
__device__ __forceinline__ void gload16(const f16* g, f16* l) {
  __builtin_amdgcn_global_load_lds(
      (const __attribute__((address_space(1))) unsigned int*)g,
      (__attribute__((address_space(3))) unsigned int*)l, 16, 0, 0);
}

// ---------------------------------------------------------------------------
// 1) prep: W_effT[i][o][c] = f16( lng[i][c] * W[i][c][o] * (scaleQ) ), transposed via LDS tile.
//    Bias partials bpart[zi][cblk][o] = sum_{c in blk} lnb[c]*W[c][o]  (no atomics).
__global__ __launch_bounds__(256) void k_prep(
    const float* __restrict__ Wq, const float* __restrict__ Wk,
    const float* __restrict__ ln1g, const float* __restrict__ ln1b,
    const float* __restrict__ ln2g, const float* __restrict__ ln2b,
    f16* __restrict__ WqT, f16* __restrict__ WkT,
    float* __restrict__ bpart)
{
  __shared__ float td[64][65];
  __shared__ float bred[4][64];
  int zi = blockIdx.z; int i = zi % 6; bool isQ = zi < 6;
  const float* W  = (isQ ? Wq  : Wk ) + (size_t)i*2048*2048;
  const float* g  = (isQ ? ln1g: ln2g) + i*2048;
  const float* lb = (isQ ? ln1b: ln2b) + i*2048;
  f16*   WT   = (isQ ? WqT : WkT) + (size_t)i*2048*2048;
  float scale = isQ ? SCALE_Q : 1.0f;
  int c0 = blockIdx.y*64, o0 = blockIdx.x*64;
  int t = threadIdx.x; int ol = t & 63; int r0 = t >> 6;
  float bp = 0.f;
  for (int rr = r0; rr < 64; rr += 4) {
    float wv = W[(size_t)(c0+rr)*2048 + o0 + ol];
    td[rr][ol] = wv * g[c0+rr] * scale;
    bp += lb[c0+rr] * wv;
  }
  bred[r0][ol] = bp;
  __syncthreads();
  for (int rr = r0; rr < 64; rr += 4)
    WT[(size_t)(o0+rr)*2048 + c0 + ol] = (f16)td[ol][rr];
  if (r0 == 0)
    bpart[((size_t)zi*32 + blockIdx.y)*2048 + o0 + ol] =
        bred[0][ol] + bred[1][ol] + bred[2][ol] + bred[3][ol];
}

__global__ __launch_bounds__(256) void k_biasfin(
    const float* __restrict__ bq, const float* __restrict__ bk,
    const float* __restrict__ bpart,
    float* __restrict__ bqe, float* __restrict__ bke)
{
  int idx = blockIdx.x*256 + threadIdx.x;   // 0..24575; zi = idx>>11
  const float* pp = bpart + (size_t)(idx >> 11)*32*2048 + (idx & 2047);
  float s = 0.f;
  #pragma unroll 8
  for (int j = 0; j < 32; ++j) s += pp[(size_t)j*2048];
  if (idx < 12288) bqe[idx] = (bq[idx] + s) * SCALE_Q;
  else { int j = idx - 12288; bke[j] = bk[j] + s; }
}

// ---------------------------------------------------------------------------
// 2) row LN stats + normalized f16 tensors for the 4 modalities used in attention
__global__ __launch_bounds__(256) void k_xnorm(
    const float* __restrict__ x0, const float* __restrict__ x1,
    const float* __restrict__ x2, const float* __restrict__ x3,
    f16* __restrict__ xn)
{
  int row = blockIdx.x; int s = blockIdx.y; int t = threadIdx.x;
  const float* xp = (s==0?x0: s==1?x1: s==2?x2: x3) + (size_t)row*2048;
  float4 v0 = *(const float4*)&xp[t*4];
  float4 v1 = *(const float4*)&xp[1024 + t*4];
  float s1 = v0.x+v0.y+v0.z+v0.w + v1.x+v1.y+v1.z+v1.w;
  float s2 = v0.x*v0.x+v0.y*v0.y+v0.z*v0.z+v0.w*v0.w
           + v1.x*v1.x+v1.y*v1.y+v1.z*v1.z+v1.w*v1.w;
  #pragma unroll
  for (int m = 1; m < 64; m <<= 1){ s1 += __shfl_xor(s1,m); s2 += __shfl_xor(s2,m); }
  __shared__ float rs[8];
  int w = t>>6, lane = t&63;
  if (lane==0){ rs[w]=s1; rs[4+w]=s2; }
  __syncthreads();
  s1 = rs[0]+rs[1]+rs[2]+rs[3];
  s2 = rs[4]+rs[5]+rs[6]+rs[7];
  float mean = s1 * (1.f/2048.f);
  float var  = s2 * (1.f/2048.f) - mean*mean;
  float rstd = rsqrtf(var + 1e-5f);
  f16* op = xn + ((size_t)s*2048 + row)*2048;
  op[t*4+0] = (f16)((v0.x-mean)*rstd); op[t*4+1] = (f16)((v0.y-mean)*rstd);
  op[t*4+2] = (f16)((v0.z-mean)*rstd); op[t*4+3] = (f16)((v0.w-mean)*rstd);
  op[1024+t*4+0] = (f16)((v1.x-mean)*rstd); op[1024+t*4+1] = (f16)((v1.y-mean)*rstd);
  op[1024+t*4+2] = (f16)((v1.z-mean)*rstd); op[1024+t*4+3] = (f16)((v1.w-mean)*rstd);
}

// ---------------------------------------------------------------------------
// 3) per-modality mean over T * softmax(modality_weights)[j] -> first half of m
__global__ __launch_bounds__(256) void k_modmean(
    const float* __restrict__ x0, const float* __restrict__ x1, const float* __restrict__ x2,
    const float* __restrict__ x3, const float* __restrict__ x4, const float* __restrict__ x5,
    const float* __restrict__ mw, float* __restrict__ m)
{
  int j = blockIdx.z, b = blockIdx.y;
  int c = blockIdx.x*256 + threadIdx.x;
  const float* xp = (j==0?x0: j==1?x1: j==2?x2: j==3?x3: j==4?x4: x5)
                    + ((size_t)b*512)*2048 + c;
  float s = 0.f;
  for (int tt = 0; tt < 512; ++tt) s += xp[(size_t)tt*2048];
  float w0=mw[0],w1=mw[1],w2=mw[2],w3=mw[3],w4=mw[4],w5=mw[5];
  float mx = fmaxf(fmaxf(fmaxf(w0,w1),fmaxf(w2,w3)),fmaxf(w4,w5));
  float den = __expf(w0-mx)+__expf(w1-mx)+__expf(w2-mx)+__expf(w3-mx)+__expf(w4-mx)+__expf(w5-mx);
  float wj = __expf(mw[j]-mx)/den;
  m[(size_t)b*24576 + (size_t)j*2048 + c] = s * (1.f/512.f) * wj;
}

// ---------------------------------------------------------------------------
// 4) batched f16 MFMA GEMM: QK[p] = xn[slot(p)] @ W_effT[p]^T + bias_eff[p]
//    m97 structure: 128x128 tile, BK=32, 4 waves, global_load_lds(16B), linear LDS dbuf
__global__ __launch_bounds__(256) void k_gemm_qk(
    const f16* __restrict__ xn, const f16* __restrict__ WqT, const f16* __restrict__ WkT,
    const float* __restrict__ bqe, const float* __restrict__ bke,
    f16* __restrict__ qk)
{
  __shared__ __align__(16) f16 As[2][128][32];
  __shared__ __align__(16) f16 Bs[2][128][32];
  int p = blockIdx.z;
  int m0 = blockIdx.y * 128, n0 = blockIdx.x * 128;
  const f16* A = xn + (size_t)c_slot[p]*(2048*2048) + (size_t)m0*2048;
  const f16* B = (p < 6 ? WqT + (size_t)p*(2048*2048) : WkT + (size_t)(p-6)*(2048*2048))
                 + (size_t)n0*2048;
  const float* bias = (p < 6 ? bqe + p*2048 : bke + (p-6)*2048) + n0;
  f16* C = qk + (size_t)p*(2048*2048) + (size_t)m0*2048 + n0;

  int t = threadIdx.x;
  int lane = t & 63, w = t >> 6;
  int wm = (w & 1) * 64, wn = (w >> 1) * 64;
  int r = lane & 15, g8 = (lane >> 4) * 8;

  // staging geometry: wave w covers rows [w*32, w*32+32) in two 16-row (1KB) chunks.
  // lane l -> row chunkbase + (l>>2), f16-col (l&3)*8  (matches LDS base+lane*16)
  int srow = w*32 + (lane >> 2);
  int scol = (lane & 3) * 8;
  const f16* Ag0 = A + (size_t)srow*2048 + scol;
  const f16* Ag1 = A + (size_t)(srow+16)*2048 + scol;
  const f16* Bg0 = B + (size_t)srow*2048 + scol;
  const f16* Bg1 = B + (size_t)(srow+16)*2048 + scol;

  f32x4 acc[4][4] = {};

  #define STAGE(buf, k0)                               \
    gload16(Ag0 + (k0), &As[buf][w*32     ][0]);       \
    gload16(Ag1 + (k0), &As[buf][w*32 + 16][0]);       \
    gload16(Bg0 + (k0), &Bs[buf][w*32     ][0]);       \
    gload16(Bg1 + (k0), &Bs[buf][w*32 + 16][0]);

  STAGE(0, 0)
  __syncthreads();

  for (int step = 0; step < 64; ++step) {
    int cur = step & 1;
    if (step < 63) { STAGE(cur ^ 1, (step + 1) * 32) }
    f16x8 af[4], bf[4];
    #pragma unroll
    for (int i = 0; i < 4; ++i) af[i] = *(const f16x8*)&As[cur][wm + i*16 + r][g8];
    #pragma unroll
    for (int j = 0; j < 4; ++j) bf[j] = *(const f16x8*)&Bs[cur][wn + j*16 + r][g8];
    #pragma unroll
    for (int i = 0; i < 4; ++i)
      #pragma unroll
      for (int j = 0; j < 4; ++j)
        acc[i][j] = __builtin_amdgcn_mfma_f32_16x16x32_f16(af[i], bf[j], acc[i][j], 0,0,0);
    __syncthreads();   // drains vmcnt (staged loads) + orders LDS reuse
  }
  #undef STAGE

  int cq = lane & 15, rg = (lane >> 4) * 4;
  #pragma unroll
  for (int i = 0; i < 4; ++i)
    #pragma unroll
    for (int j = 0; j < 4; ++j) {
      int n = wn + j*16 + cq;
      float bz = bias[n];
      #pragma unroll
      for (int reg = 0; reg < 4; ++reg) {
        int mm = wm + i*16 + rg + reg;
        C[(size_t)mm*2048 + n] = (f16)(acc[i][j][reg] + bz);
      }
    }
}

// ---------------------------------------------------------------------------
// 5) attention: per (h,b,module) compute softmax(Q K^T) column means -> meanA[i][b][h][k]
//    scores kept fully in registers (32 x f32x4 per lane = 16 q-rows x 512 k per wave-tile)
__global__ __launch_bounds__(256) void k_attn(
    const f16* __restrict__ qk, float* __restrict__ meanA)
{
  __shared__ float cs[512];
  int h = blockIdx.x, b = blockIdx.y, i = blockIdx.z;
  int t = threadIdx.x; int lane = t & 63; int w = t >> 6;
  for (int q = t; q < 512; q += 256) cs[q] = 0.f;
  __syncthreads();
  const f16* Q = qk + (size_t)i    *(2048*2048) + (size_t)(b*512)*2048 + h*128;
  const f16* K = qk + (size_t)(6+i)*(2048*2048) + (size_t)(b*512)*2048 + h*128;
  int r = lane & 15, g8 = (lane >> 4) * 8;
  const f32x4 vz = {0.f,0.f,0.f,0.f};
  float colacc[32];
  #pragma unroll
  for (int kf = 0; kf < 32; ++kf) colacc[kf] = 0.f;

  for (int qt = 0; qt < 8; ++qt) {
    int q0 = w*128 + qt*16;
    f16x8 aq[4];
    #pragma unroll
    for (int d = 0; d < 4; ++d)
      aq[d] = *(const f16x8*)&Q[(size_t)(q0 + r)*2048 + d*32 + g8];
    f32x4 acc[32];
    #pragma unroll
    for (int kf = 0; kf < 32; ++kf) acc[kf] = vz;
    #pragma unroll
    for (int kf = 0; kf < 32; ++kf) {
      #pragma unroll
      for (int d = 0; d < 4; ++d) {
        f16x8 bk = *(const f16x8*)&K[(size_t)(kf*16 + r)*2048 + d*32 + g8];
        acc[kf] = __builtin_amdgcn_mfma_f32_16x16x32_f16(aq[d], bk, acc[kf], 0,0,0);
      }
    }
    // rows live in regs: row=(lane>>4)*4+reg, col=kf*16+(lane&15)
    f32x4 mx = acc[0];
    #pragma unroll
    for (int kf = 1; kf < 32; ++kf) mx = vmax4(mx, acc[kf]);
    #pragma unroll
    for (int msk = 1; msk <= 8; msk <<= 1) mx = vmax4(mx, shflx4(mx, msk));
    f32x4 se = vz;
    #pragma unroll
    for (int kf = 0; kf < 32; ++kf) { f32x4 pv = vexp4(acc[kf] - mx); acc[kf] = pv; se += pv; }
    #pragma unroll
    for (int msk = 1; msk <= 8; msk <<= 1) se += shflx4(se, msk);
    f32x4 inv; inv[0]=1.f/se[0]; inv[1]=1.f/se[1]; inv[2]=1.f/se[2]; inv[3]=1.f/se[3];
    #pragma unroll
    for (int kf = 0; kf < 32; ++kf) {
      f32x4 pp = acc[kf] * inv;
      float c = pp[0]+pp[1]+pp[2]+pp[3];
      c += __shfl_xor(c, 16); c += __shfl_xor(c, 32);
      colacc[kf] += c;
    }
  }
  if (lane < 16) {
    #pragma unroll
    for (int kf = 0; kf < 32; ++kf) atomicAdd(&cs[kf*16 + lane], colacc[kf]);
  }
  __syncthreads();
  float* out = meanA + (((size_t)i*4 + b)*16 + h)*512;
  for (int q = t; q < 512; q += 256) out[q] = cs[q] * (1.f/512.f);
}

// ---------------------------------------------------------------------------
// 6) U[i][b][h][c] = sum_k meanA[i][b][h][k] * kv_i[b][k][c]
__global__ __launch_bounds__(256) void k_u(
    const float* __restrict__ img, const float* __restrict__ aud, const float* __restrict__ agt,
    const float* __restrict__ meanA, float* __restrict__ U)
{
  __shared__ float sma[8192];    // [k][h] transposed, 32 KB
  int i = blockIdx.z, b = blockIdx.y;
  int c = blockIdx.x*256 + threadIdx.x;
  size_t base = (((size_t)i*4 + b)*16)*512;
  for (int idx = threadIdx.x; idx < 8192; idx += 256) {
    int k = idx >> 4, hh = idx & 15;
    sma[idx] = meanA[base + (size_t)hh*512 + k];
  }
  __syncthreads();
  const float* kv = (i==0? img : i==1? aud : i==2? agt : i==3? aud : agt)
                    + ((size_t)b*512)*2048 + c;
  f32x4 a0={0,0,0,0}, a1={0,0,0,0}, a2={0,0,0,0}, a3={0,0,0,0};
  for (int k = 0; k < 512; ++k) {
    float x = kv[(size_t)k*2048];
    const f32x4* sp = (const f32x4*)&sma[k*16];
    a0 += sp[0]*x; a1 += sp[1]*x; a2 += sp[2]*x; a3 += sp[3]*x;
  }
  size_t ob = (((size_t)i*4 + b)*16)*2048 + c;
  #pragma unroll
  for (int hh = 0; hh < 4; ++hh) { U[ob + (size_t)hh*2048] = a0[hh]; }
  #pragma unroll
  for (int hh = 0; hh < 4; ++hh) { U[ob + (size_t)(4+hh)*2048] = a1[hh]; }
  #pragma unroll
  for (int hh = 0; hh < 4; ++hh) { U[ob + (size_t)(8+hh)*2048] = a2[hh]; }
  #pragma unroll
  for (int hh = 0; hh < 4; ++hh) { U[ob + (size_t)(12+hh)*2048] = a3[hh]; }
}

// ---------------------------------------------------------------------------
// 7) am[i][b][hd] = sum_c U[i][b][h][c]*Wv[i][c][hd] (+bv), split-K atomics
__global__ __launch_bounds__(256) void k_am(
    const float* __restrict__ Wv, const float* __restrict__ bv,
    const float* __restrict__ U, float* __restrict__ am)
{
  __shared__ float su[4][2][256];
  int i = blockIdx.z, cc = blockIdx.y, ot = blockIdx.x;
  int t = threadIdx.x;
  int o = ot*256 + t, h0 = ot*2, c0 = cc*256;
  for (int idx = t; idx < 2048; idx += 256) {
    int b_ = idx >> 9, rem = idx & 511, hl_ = rem >> 8, c_ = rem & 255;
    su[b_][hl_][c_] = U[(((size_t)i*4 + b_)*16 + h0 + hl_)*2048 + c0 + c_];
  }
  __syncthreads();
  int hl = (t >> 7) & 1;
  float a0=0,a1=0,a2=0,a3=0;
  const float* wp = Wv + (size_t)i*2048*2048 + (size_t)c0*2048 + o;
  for (int c = 0; c < 256; ++c) {
    float wv = wp[(size_t)c*2048];
    a0 += su[0][hl][c]*wv; a1 += su[1][hl][c]*wv;
    a2 += su[2][hl][c]*wv; a3 += su[3][hl][c]*wv;
  }
  if (cc == 0) { float bz = bv[i*2048+o]; a0+=bz; a1+=bz; a2+=bz; a3+=bz; }
  atomicAdd(&am[((size_t)i*4+0)*2048 + o], a0);
  atomicAdd(&am[((size_t)i*4+1)*2048 + o], a1);
  atomicAdd(&am[((size_t)i*4+2)*2048 + o], a2);
  atomicAdd(&am[((size_t)i*4+3)*2048 + o], a3);
}

// 8) m[b][6H + i*H + o] += 0.2*(sum_hd am[i][b][hd]*Wo[i][hd][o] + bo)
__global__ __launch_bounds__(256) void k_y(
    const float* __restrict__ Wo, const float* __restrict__ bo,
    const float* __restrict__ am, float* __restrict__ m)
{
  __shared__ float sa[4][256];
  int i = blockIdx.z, kc = blockIdx.y, ot = blockIdx.x;
  int t = threadIdx.x;
  int o = ot*256 + t;
  for (int idx = t; idx < 1024; idx += 256) {
    int b_ = idx >> 8, k_ = idx & 255;
    sa[b_][k_] = am[((size_t)i*4 + b_)*2048 + kc*256 + k_];
  }
  __syncthreads();
  float a0=0,a1=0,a2=0,a3=0;
  const float* wp = Wo + (size_t)i*2048*2048 + (size_t)(kc*256)*2048 + o;
  for (int k = 0; k < 256; ++k) {
    float wv = wp[(size_t)k*2048];
    a0 += sa[0][k]*wv; a1 += sa[1][k]*wv; a2 += sa[2][k]*wv; a3 += sa[3][k]*wv;
  }
  if (kc == 0) { float bz = bo[i*2048+o]; a0+=bz; a1+=bz; a2+=bz; a3+=bz; }
  size_t col = 12288 + (size_t)i*2048 + o;
  atomicAdd(&m[0*24576 + col], 0.2f*a0);
  atomicAdd(&m[1*24576 + col], 0.2f*a1);
  atomicAdd(&m[2*24576 + col], 0.2f*a2);
  atomicAdd(&m[3*24576 + col], 0.2f*a3);
}

// ---------------------------------------------------------------------------
// 9) gate MLP first layer: g1[b][n] = sum_C m[b][C]*W1[C][n] (+b1), split-K atomics
__global__ __launch_bounds__(256) void k_w1(
    const float* __restrict__ W1, const float* __restrict__ b1,
    const float* __restrict__ m, float* __restrict__ g1)
{
  __shared__ float sm[4][256];
  int kc = blockIdx.y, ng = blockIdx.x;
  int t = threadIdx.x;
  for (int idx = t; idx < 1024; idx += 256) {
    int b_ = idx >> 8, j_ = idx & 255;
    sm[b_][j_] = m[(size_t)b_*24576 + kc*256 + j_];
  }
  __syncthreads();
  int n = ng*256 + t;
  float a0=0,a1=0,a2=0,a3=0;
  const float* wp = W1 + (size_t)(kc*256)*2048 + n;
  for (int j = 0; j < 256; ++j) {
    float wv = wp[(size_t)j*2048];
    a0 += sm[0][j]*wv; a1 += sm[1][j]*wv; a2 += sm[2][j]*wv; a3 += sm[3][j]*wv;
  }
  if (kc == 0) { float bz = b1[n]; a0+=bz; a1+=bz; a2+=bz; a3+=bz; }
  atomicAdd(&g1[0*2048+n], a0); atomicAdd(&g1[1*2048+n], a1);
  atomicAdd(&g1[2*2048+n], a2); atomicAdd(&g1[3*2048+n], a3);
}

__global__ __launch_bounds__(256) void k_silu(const float* __restrict__ g1, float* __restrict__ h1)
{
  int idx = blockIdx.x*256 + threadIdx.x;
  float v = g1[idx];
  h1[idx] = v / (1.f + __expf(-v));
}

// 10) second layer: g2[b][o] = sum_n h1[b][n]*W2[n][o] (+b2), split-K atomics
__global__ __launch_bounds__(256) void k_w2(
    const float* __restrict__ W2, const float* __restrict__ b2,
    const float* __restrict__ h1, float* __restrict__ g2)
{
  __shared__ float sh[4][256];
  int kc = blockIdx.y, og = blockIdx.x;
  int t = threadIdx.x;
  for (int idx = t; idx < 1024; idx += 256) {
    int b_ = idx >> 8, j_ = idx & 255;
    sh[b_][j_] = h1[(size_t)b_*2048 + kc*256 + j_];
  }
  __syncthreads();
  int o = og*256 + t;
  float a0=0,a1=0,a2=0,a3=0;
  const float* wp = W2 + (size_t)(kc*256)*24576 + o;
  for (int j = 0; j < 256; ++j) {
    float wv = wp[(size_t)j*24576];
    a0 += sh[0][j]*wv; a1 += sh[1][j]*wv; a2 += sh[2][j]*wv; a3 += sh[3][j]*wv;
  }
  if (kc == 0) { float bz = b2[o]; a0+=bz; a1+=bz; a2+=bz; a3+=bz; }
  atomicAdd(&g2[0*24576+o], a0); atomicAdd(&g2[1*24576+o], a1);
  atomicAdd(&g2[2*24576+o], a2); atomicAdd(&g2[3*24576+o], a3);
}

// 11) final LN stats over 24576 per batch row
__global__ __launch_bounds__(256) void k_lnstats(const float* __restrict__ m, float* __restrict__ st)
{
  int b = blockIdx.x; int t = threadIdx.x;
  const float* mr = m + (size_t)b*24576;
  float s1=0.f, s2=0.f;
  for (int k = 0; k < 24; ++k) {
    f32x4 v = *(const f32x4*)&mr[(k*256 + t)*4];
    s1 += v[0]+v[1]+v[2]+v[3];
    s2 += v[0]*v[0]+v[1]*v[1]+v[2]*v[2]+v[3]*v[3];
  }
  #pragma unroll
  for (int msk = 1; msk < 64; msk <<= 1){ s1 += __shfl_xor(s1,msk); s2 += __shfl_xor(s2,msk); }
  __shared__ float rs[8];
  int w = t>>6, lane = t&63;
  if (lane==0){ rs[w]=s1; rs[4+w]=s2; }
  __syncthreads();
  if (t == 0) {
    float S1 = rs[0]+rs[1]+rs[2]+rs[3];
    float S2 = rs[4]+rs[5]+rs[6]+rs[7];
    float mean = S1*(1.f/24576.f);
    float var  = S2*(1.f/24576.f) - mean*mean;
    st[b*2]   = mean;
    st[b*2+1] = rsqrtf(var + 1e-5f);
  }
}

// 12) out = LN(m)*sigmoid(g2)
__global__ __launch_bounds__(256) void k_final(
    const float* __restrict__ m, const float* __restrict__ g2,
    const float* __restrict__ ng, const float* __restrict__ nb,
    const float* __restrict__ st, float* __restrict__ out)
{
  int idx = blockIdx.x*256 + threadIdx.x;
  int b = idx / 24576, o = idx % 24576;
  float mv = m[idx];
  float lnv = (mv - st[b*2]) * st[b*2+1] * ng[o] + nb[o];
  float gate = 1.f / (1.f + __expf(-g2[idx]));
  out[idx] = lnv * gate;
}

// ---------------------------------------------------------------------------
extern "C" void kernel_launch(void* const* d_in, const int* in_sizes, int n_in,
                              void* d_out, int out_size, void* d_ws, size_t ws_size,
                              hipStream_t stream)
{
  const float* x_text = (const float*)d_in[0];
  const float* x_img  = (const float*)d_in[1];
  const float* x_aud  = (const float*)d_in[2];
  const float* x_vid  = (const float*)d_in[3];
  const float* x_doc  = (const float*)d_in[4];
  const float* x_agt  = (const float*)d_in[5];
  const float* Wq = (const float*)d_in[6];
  const float* Wk = (const float*)d_in[7];
  const float* Wv = (const float*)d_in[8];
  const float* Wo = (const float*)d_in[9];
  const float* bq = (const float*)d_in[10];
  const float* bk = (const float*)d_in[11];
  const float* bv = (const float*)d_in[12];
  const float* bo = (const float*)d_in[13];
  const float* ln1g = (const float*)d_in[14];
  const float* ln1b = (const float*)d_in[15];
  const float* ln2g = (const float*)d_in[16];
  const float* ln2b = (const float*)d_in[17];
  const float* mw   = (const float*)d_in[18];
  const float* gW1  = (const float*)d_in[19];
  const float* gb1  = (const float*)d_in[20];
  const float* gW2  = (const float*)d_in[21];
  const float* gb2  = (const float*)d_in[22];
  const float* ngm  = (const float*)d_in[23];
  const float* nbm  = (const float*)d_in[24];
  float* out = (float*)d_out;

  char* ws = (char*)d_ws;
  // layout (bytes):
  f16*   WqT   = (f16*)  (ws + 0);                    //  48 MB
  f16*   WkT   = (f16*)  (ws + 50331648);             //  48 MB
  f16*   QK    = (f16*)  (ws + 100663296);            //  96 MB
  f16*   XN    = (f16*)  (ws + 201326592);            //  32 MB
  float* BPART = (float*)(ws + 234881024);            //   3 MB (12*32*2048)
  float* MEANA = (float*)(ws + 238026752);            // 768 KB
  float* U     = (float*)(ws + 238813184);            //   3 MB
  // --- contiguous zeroed region (atomic targets) ---
  const size_t Z0 = 241958912;
  float* AM    = (float*)(ws + Z0);                   // 192 KB
  float* M     = (float*)(ws + Z0 + 196608);          // 384 KB
  float* G1    = (float*)(ws + Z0 + 589824);          //  32 KB
  float* G2    = (float*)(ws + Z0 + 622592);          // 384 KB
  const size_t ZBYTES = 1015808;
  // --- end zero region ---
  float* BQE   = (float*)(ws + Z0 + 1015808);         //  48 KB
  float* BKE   = (float*)(ws + Z0 + 1064960);         //  48 KB
  float* H1    = (float*)(ws + Z0 + 1114112);         //  32 KB
  float* LNST  = (float*)(ws + Z0 + 1146880);         //  32 B
  (void)ws_size; (void)in_sizes; (void)n_in; (void)out_size;
  (void)x_vid; (void)x_doc;

  hipMemsetAsync(ws + Z0, 0, ZBYTES, stream);

  k_prep<<<dim3(32,32,12), 256, 0, stream>>>(Wq, Wk, ln1g, ln1b, ln2g, ln2b,
                                             WqT, WkT, BPART);
  k_biasfin<<<96, 256, 0, stream>>>(bq, bk, BPART, BQE, BKE);
  k_xnorm<<<dim3(2048,4), 256, 0, stream>>>(x_text, x_img, x_aud, x_agt, XN);
  k_modmean<<<dim3(8,4,6), 256, 0, stream>>>(x_text, x_img, x_aud, x_vid, x_doc, x_agt, mw, M);
  k_gemm_qk<<<dim3(16,16,12), 256, 0, stream>>>(XN, WqT, WkT, BQE, BKE, QK);
  k_attn<<<dim3(16,4,6), 256, 0, stream>>>(QK, MEANA);
  k_u<<<dim3(8,4,6), 256, 0, stream>>>(x_img, x_aud, x_agt, MEANA, U);
  k_am<<<dim3(8,8,6), 256, 0, stream>>>(Wv, bv, U, AM);
  k_y<<<dim3(8,8,6), 256, 0, stream>>>(Wo, bo, AM, M);
  k_w1<<<dim3(8,96), 256, 0, stream>>>(gW1, gb1, M, G1);
  k_silu<<<32, 256, 0, stream>>>(G1, H1);
  k_w2<<<dim3(96,8), 256, 0, stream>>>(gW2, gb2, H1, G2);
  k_lnstats<<<4, 256, 0, stream>>>(M, LNST);
  k_final<<<384, 256, 0, stream>>>(M, G2, ngm, nbm, LNST, out);
}